// Round 4
// baseline (6373317.188 us; speedup 1.0000x reference)
//
#include <hip/hip_runtime.h>
#include <hip/hip_bf16.h>
#include <math.h>

#define SEQ 4096
#define HDIM 1024
#define G3 3072

#define NBLK 256          // persistent blocks, 1 per CU
#define NXCD 8
#define JPB 32            // h indices per block
#define JPW 4             // h indices per wave (8 waves)
#define ROWS 12           // W_hh rows per wave (3 gates x 4 idx)

typedef float    f32x4 __attribute__((ext_vector_type(4)));
typedef float    f32x2 __attribute__((ext_vector_type(2)));
typedef unsigned u32x4 __attribute__((ext_vector_type(4)));
typedef unsigned u32x2 __attribute__((ext_vector_type(2)));

// ws layout (dwords):
// [0, SEQ*G3)            gi_all (50.33 MB)
// [PAIRS_OFF, +32768)    8 XCD regions x (2 bufs x 1024 pairs x (val,tag))
// [CNT_OFF, +8)          per-XCD claim counters
#define GI_ELEMS  (SEQ * G3)
#define PAIRS_OFF GI_ELEMS
#define REGION_DW 4096
#define CNT_OFF   (PAIRS_OFF + NXCD * REGION_DW)
#define WS_NEEDED_BYTES ((size_t)(CNT_OFF + NXCD) * 4)

__global__ void k_init(float* ws) {
    unsigned* pairs = (unsigned*)(ws + PAIRS_OFF);
    int tid = blockIdx.x * 256 + threadIdx.x;    // 0..16383: one pair each
    u32x2 z; z.x = 0u; z.y = 0u;
    *(u32x2*)(pairs + (size_t)tid * 2) = z;
    if (tid < NXCD) ((unsigned*)(ws + CNT_OFF))[tid] = 0u;
}

__global__ void k_ws_too_small(float* out) {
    if (threadIdx.x < 2) out[threadIdx.x] = -12345.0f;  // sentinel
}

// ---------------- K1: gi_all = emb[X] @ W_ih^T + b_ih ----------------
__global__ __launch_bounds__(256)
void k_gi(const int* __restrict__ X, const float* __restrict__ emb,
          const float* __restrict__ W_ih, const float* __restrict__ b_ih,
          float* __restrict__ gi) {
    __shared__ float As[16][64];
    __shared__ float Bs[16][64];
    __shared__ int Xl[64];

    const int t0 = blockIdx.x * 64;
    const int m0 = blockIdx.y * 64;
    const int tid = threadIdx.x;

    if (tid < 64) Xl[tid] = X[t0 + tid];
    __syncthreads();

    const int lrow = tid & 63;
    const int kq = tid >> 6;
    const int tx = tid & 15, ty = tid >> 4;

    const float* embr = emb + (size_t)Xl[lrow] * HDIM;
    const float* wrow = W_ih + (size_t)(m0 + lrow) * HDIM;

    float acc[4][4] = {};

    for (int k0 = 0; k0 < HDIM; k0 += 16) {
        float4 a = *(const float4*)(embr + k0 + kq * 4);
        float4 bv = *(const float4*)(wrow + k0 + kq * 4);
        __syncthreads();
        As[kq * 4 + 0][lrow] = a.x;  As[kq * 4 + 1][lrow] = a.y;
        As[kq * 4 + 2][lrow] = a.z;  As[kq * 4 + 3][lrow] = a.w;
        Bs[kq * 4 + 0][lrow] = bv.x; Bs[kq * 4 + 1][lrow] = bv.y;
        Bs[kq * 4 + 2][lrow] = bv.z; Bs[kq * 4 + 3][lrow] = bv.w;
        __syncthreads();
        #pragma unroll
        for (int k = 0; k < 16; ++k) {
            float4 av = *(const float4*)&As[k][ty * 4];
            float4 bw = *(const float4*)&Bs[k][tx * 4];
            float a_[4] = {av.x, av.y, av.z, av.w};
            float b_[4] = {bw.x, bw.y, bw.z, bw.w};
            #pragma unroll
            for (int i = 0; i < 4; ++i)
                #pragma unroll
                for (int j = 0; j < 4; ++j)
                    acc[i][j] += a_[i] * b_[j];
        }
    }

    float4 bj = *(const float4*)&b_ih[m0 + tx * 4];
    #pragma unroll
    for (int i = 0; i < 4; ++i) {
        float4 o;
        o.x = acc[i][0] + bj.x; o.y = acc[i][1] + bj.y;
        o.z = acc[i][2] + bj.z; o.w = acc[i][3] + bj.w;
        *(float4*)&gi[(size_t)(t0 + ty * 4 + i) * G3 + m0 + tx * 4] = o;
    }
}

// ---- DPP wave64 sum (no LDS); result broadcast via readlane(63) ----
template<int CTRL>
__device__ __forceinline__ float dpp_add(float x) {
    int t = __builtin_amdgcn_update_dpp(0, __float_as_int(x), CTRL, 0xF, 0xF, true);
    return x + __int_as_float(t);
}
__device__ __forceinline__ float wave_reduce(float s) {
    s = dpp_add<0x111>(s);   // row_shr:1
    s = dpp_add<0x112>(s);   // row_shr:2
    s = dpp_add<0x114>(s);   // row_shr:4
    s = dpp_add<0x118>(s);   // row_shr:8
    s = dpp_add<0x142>(s);   // row_bcast:15
    s = dpp_add<0x143>(s);   // row_bcast:31
    return __int_as_float(__builtin_amdgcn_readlane(__float_as_int(s), 63));
}

// ---------------- K2: per-XCD replicated GRU scan ----------------
// 256 blocks x 512 threads, 1/CU. Blocks discover their XCD (XCC_ID) and
// claim a shard slot; each XCD's 32 blocks compute the FULL GRU step,
// exchanging h only through their own XCD's L2 (sc0, no L2 bypass).
__global__ __launch_bounds__(512, 2)
void k_scan(const float* __restrict__ W_hh, const float* __restrict__ b_hh,
            float* ws) {
    __shared__ float hl[HDIM];          // 4 KB staged h
    __shared__ float pad[20480];        // 80 KB: force 1 block/CU
    __shared__ unsigned claim_s;

    const int tid = threadIdx.x;
    const int w = tid >> 6, ln = tid & 63;

    unsigned* cnt = (unsigned*)(ws + CNT_OFF);
    if (tid == 0) {
        unsigned xcd;
        asm volatile("s_getreg_b32 %0, hwreg(HW_REG_XCC_ID)" : "=s"(xcd));
        xcd &= 7u;
        unsigned slot = atomicAdd(&cnt[xcd], 1u) & 31u;
        claim_s = (xcd << 8) | slot;
    }
    pad[tid] = 0.0f;                    // keep pad allocated
    __syncthreads();
    const unsigned xcd  = claim_s >> 8;
    const unsigned slot = claim_s & 255u;
    const int j0  = (int)slot * JPB;    // block's first h index
    const int jw  = j0 + w * JPW;       // wave's first h index
    const int il  = ln & 3;
    const int jme = jw + il;            // lane-group's h index

    unsigned* reg0 = (unsigned*)(ws + PAIRS_OFF) + (size_t)xcd * REGION_DW;
    const float* gi = ws;

    // ---- weights: 12 rows x 16 cols/lane, pinned in VGPRs ----
    f32x4 wr[ROWS][4];
    #pragma unroll
    for (int rr = 0; rr < ROWS; ++rr) {
        const int g = rr >> 2, i = rr & 3;
        const float* src = W_hh + (size_t)(g * HDIM + jw + i) * HDIM + ln * 4;
        #pragma unroll
        for (int c = 0; c < 4; ++c) wr[rr][c] = *(const f32x4*)(src + 256 * c);
    }

    const float br = b_hh[jme];
    const float bz = b_hh[HDIM + jme];
    const float bn = b_hh[2 * HDIM + jme];

    for (int t = 0; t < SEQ; ++t) {
        const unsigned tt = (unsigned)t;

        #pragma unroll
        for (int rr = 0; rr < ROWS; ++rr)
            asm volatile("" : "+v"(wr[rr][0]), "+v"(wr[rr][1]),
                              "+v"(wr[rr][2]), "+v"(wr[rr][3]));

        // gi prefetch (cached; completes under the poll)
        const float* gp = gi + (size_t)t * G3 + jme;
        const float gi_r = gp[0], gi_z = gp[HDIM], gi_n = gp[2 * HDIM];

        // ---- poll own slice (2 pairs/lane, tag==t fused with data) ----
        unsigned* qb = reg0 + ((t + 1) & 1) * 2048 + 512 * w + 4 * ln;
        u32x4 p;
        int spin = 0;
        for (;;) {
            asm volatile("global_load_dwordx4 %0, %1, off sc0\n\t"
                         "s_waitcnt vmcnt(0)"
                         : "=&v"(p) : "v"(qb) : "memory");
            if (__all((p.y == tt) & (p.w == tt))) break;
            if (++spin > (1 << 14)) break;      // fail visibly, never hang
        }
        f32x2 h2; h2.x = __uint_as_float(p.x); h2.y = __uint_as_float(p.z);
        *(f32x2*)&hl[128 * w + 2 * ln] = h2;
        __syncthreads();
        // (no 2nd barrier needed: a wave's next-step hl overwrite is gated by
        //  all 1024 tags==t+1, and each tag store is data-dependent on that
        //  wave's hl reads this step)

        const f32x4 hv0 = *(const f32x4*)&hl[ln * 4];
        const f32x4 hv1 = *(const f32x4*)&hl[ln * 4 + 256];
        const f32x4 hv2 = *(const f32x4*)&hl[ln * 4 + 512];
        const f32x4 hv3 = *(const f32x4*)&hl[ln * 4 + 768];
        const float hp  = hl[jme];

        #define DOT16(rr) ( \
            wr[rr][0].x*hv0.x + wr[rr][0].y*hv0.y + wr[rr][0].z*hv0.z + wr[rr][0].w*hv0.w + \
            wr[rr][1].x*hv1.x + wr[rr][1].y*hv1.y + wr[rr][1].z*hv1.z + wr[rr][1].w*hv1.w + \
            wr[rr][2].x*hv2.x + wr[rr][2].y*hv2.y + wr[rr][2].z*hv2.z + wr[rr][2].w*hv2.w + \
            wr[rr][3].x*hv3.x + wr[rr][3].y*hv3.y + wr[rr][3].z*hv3.z + wr[rr][3].w*hv3.w )

        float tot[ROWS];
        #pragma unroll
        for (int rr = 0; rr < ROWS; ++rr) tot[rr] = wave_reduce(DOT16(rr));
        #undef DOT16

        // ---- gate combine + publish (lanes 0..3 of each wave) ----
        if (ln < 4) {
            const float sr = (il == 0) ? tot[0] : (il == 1) ? tot[1] : (il == 2) ? tot[2]  : tot[3];
            const float sz = (il == 0) ? tot[4] : (il == 1) ? tot[5] : (il == 2) ? tot[6]  : tot[7];
            const float sn = (il == 0) ? tot[8] : (il == 1) ? tot[9] : (il == 2) ? tot[10] : tot[11];
            const float r = 1.0f / (1.0f + __expf(-(gi_r + sr + br)));
            const float z = 1.0f / (1.0f + __expf(-(gi_z + sz + bz)));
            float xa = gi_n + r * (sn + bn);
            xa = fminf(15.0f, fmaxf(-15.0f, xa));
            const float e2 = __expf(2.0f * xa);
            const float n = (e2 - 1.0f) / (e2 + 1.0f);
            const float hnew = (1.0f - z) * n + z * hp;
            u32x2 pv; pv.x = __float_as_uint(hnew); pv.y = tt + 1u;
            unsigned* dst = reg0 + (t & 1) * 2048 + jme * 2;
            asm volatile("global_store_dwordx2 %0, %1, off sc0"
                         :: "v"(dst), "v"(pv) : "memory");
        }
    }
}

// ---------------- K3: head ----------------
__global__ void k_head(const float* __restrict__ W1, const float* __restrict__ b1,
                       const float* __restrict__ W2, const float* __restrict__ b2,
                       const float* __restrict__ ws, float* __restrict__ out) {
    // final h: region 0, buffer[4095&1=1], values at even dwords
    const unsigned* hpair = (const unsigned*)(ws + PAIRS_OFF) + 2048;
    const int ln = threadIdx.x;
    __shared__ float zsh[8];
    for (int m = 0; m < 8; ++m) {
        float s = 0.0f;
        #pragma unroll
        for (int c = 0; c < 16; ++c) {
            const int j = c * 64 + ln;
            s += __uint_as_float(hpair[2 * j]) * W1[m * HDIM + j];
        }
        #pragma unroll
        for (int off = 32; off; off >>= 1) s += __shfl_xor(s, off);
        if (ln == 0) zsh[m] = fmaxf(s + b1[m], 0.0f);
    }
    __syncthreads();
    if (ln < 2) {
        float s = b2[ln];
        #pragma unroll
        for (int m = 0; m < 8; ++m) s += zsh[m] * W2[ln * 8 + m];
        out[ln] = 1.0f / (1.0f + expf(-s));
    }
}

extern "C" void kernel_launch(void* const* d_in, const int* in_sizes, int n_in,
                              void* d_out, int out_size, void* d_ws, size_t ws_size,
                              hipStream_t stream) {
    const int*   X    = (const int*)d_in[0];
    const float* emb  = (const float*)d_in[1];
    const float* W_ih = (const float*)d_in[2];
    const float* W_hh = (const float*)d_in[3];
    const float* b_ih = (const float*)d_in[4];
    const float* b_hh = (const float*)d_in[5];
    const float* W1   = (const float*)d_in[6];
    const float* b1   = (const float*)d_in[7];
    const float* W2   = (const float*)d_in[8];
    const float* b2   = (const float*)d_in[9];
    float* out = (float*)d_out;
    float* ws  = (float*)d_ws;

    if (ws_size < WS_NEEDED_BYTES) {
        k_ws_too_small<<<1, 64, 0, stream>>>(out);
        return;
    }

    k_init<<<dim3(64), dim3(256), 0, stream>>>(ws);
    dim3 g1(SEQ / 64, G3 / 64);
    k_gi<<<g1, dim3(256), 0, stream>>>(X, emb, W_ih, b_ih, ws);
    k_scan<<<dim3(NBLK), dim3(512), 0, stream>>>(W_hh, b_hh, ws);
    k_head<<<dim3(1), dim3(64), 0, stream>>>(W1, b1, W2, b2, ws, out);
}

// Round 5
// 11519.025 us; speedup vs baseline: 553.2861x; 553.2861x over previous
//
#include <hip/hip_runtime.h>
#include <hip/hip_bf16.h>
#include <math.h>

#define SEQ 4096
#define HDIM 1024
#define G3 3072

#define NBLK 32           // scan blocks (robust: no co-residency cliff)
#define NWAVE 8           // waves per block
#define JPW 4             // h indices per wave
#define ROWS 12           // W_hh rows per wave (3 gates x 4 idx)
#define NCOPY 4           // pair-buffer multicast copies
#define COPY_DW 4096      // dwords per copy: 2 bufs x 1024 pairs x 2

typedef float    f32x4 __attribute__((ext_vector_type(4)));
typedef float    f32x2 __attribute__((ext_vector_type(2)));
typedef unsigned u32x4 __attribute__((ext_vector_type(4)));
typedef unsigned u32x2 __attribute__((ext_vector_type(2)));

// ws layout (dwords):
// [0, SEQ*G3)              gi_all (50.33 MB)
// [PAIRS_OFF, +4*4096)     4 copies x (2 bufs x 1024 pairs x (val,tag))
#define GI_ELEMS  (SEQ * G3)
#define PAIRS_OFF GI_ELEMS
#define WS_NEEDED_BYTES ((size_t)(PAIRS_OFF + NCOPY * COPY_DW) * 4)

// zero all pair copies with DEVICE-SCOPE stores (bypass L2: readers bypass
// L2 too, so init must land at the coherence point — R4 lesson)
__global__ void k_init(float* ws) {
    unsigned* pairs = (unsigned*)(ws + PAIRS_OFF);
    int tid = blockIdx.x * 256 + threadIdx.x;   // 0..8191: one pair each
    u32x2 z; z.x = 0u; z.y = 0u;
    unsigned* p = pairs + (size_t)tid * 2;
    asm volatile("global_store_dwordx2 %0, %1, off sc0 sc1" :: "v"(p), "v"(z) : "memory");
}

__global__ void k_ws_too_small(float* out) {
    if (threadIdx.x < 2) out[threadIdx.x] = -12345.0f;  // sentinel
}

// ---------------- K1: gi_all = emb[X] @ W_ih^T + b_ih ----------------
__global__ __launch_bounds__(256)
void k_gi(const int* __restrict__ X, const float* __restrict__ emb,
          const float* __restrict__ W_ih, const float* __restrict__ b_ih,
          float* __restrict__ gi) {
    __shared__ float As[16][64];
    __shared__ float Bs[16][64];
    __shared__ int Xl[64];

    const int t0 = blockIdx.x * 64;
    const int m0 = blockIdx.y * 64;
    const int tid = threadIdx.x;

    if (tid < 64) Xl[tid] = X[t0 + tid];
    __syncthreads();

    const int lrow = tid & 63;
    const int kq = tid >> 6;
    const int tx = tid & 15, ty = tid >> 4;

    const float* embr = emb + (size_t)Xl[lrow] * HDIM;
    const float* wrow = W_ih + (size_t)(m0 + lrow) * HDIM;

    float acc[4][4] = {};

    for (int k0 = 0; k0 < HDIM; k0 += 16) {
        float4 a = *(const float4*)(embr + k0 + kq * 4);
        float4 bv = *(const float4*)(wrow + k0 + kq * 4);
        __syncthreads();
        As[kq * 4 + 0][lrow] = a.x;  As[kq * 4 + 1][lrow] = a.y;
        As[kq * 4 + 2][lrow] = a.z;  As[kq * 4 + 3][lrow] = a.w;
        Bs[kq * 4 + 0][lrow] = bv.x; Bs[kq * 4 + 1][lrow] = bv.y;
        Bs[kq * 4 + 2][lrow] = bv.z; Bs[kq * 4 + 3][lrow] = bv.w;
        __syncthreads();
        #pragma unroll
        for (int k = 0; k < 16; ++k) {
            float4 av = *(const float4*)&As[k][ty * 4];
            float4 bw = *(const float4*)&Bs[k][tx * 4];
            float a_[4] = {av.x, av.y, av.z, av.w};
            float b_[4] = {bw.x, bw.y, bw.z, bw.w};
            #pragma unroll
            for (int i = 0; i < 4; ++i)
                #pragma unroll
                for (int j = 0; j < 4; ++j)
                    acc[i][j] += a_[i] * b_[j];
        }
    }

    float4 bj = *(const float4*)&b_ih[m0 + tx * 4];
    #pragma unroll
    for (int i = 0; i < 4; ++i) {
        float4 o;
        o.x = acc[i][0] + bj.x; o.y = acc[i][1] + bj.y;
        o.z = acc[i][2] + bj.z; o.w = acc[i][3] + bj.w;
        *(float4*)&gi[(size_t)(t0 + ty * 4 + i) * G3 + m0 + tx * 4] = o;
    }
}

// ---- DPP wave64 sum; total broadcast via readlane(63) ----
template<int CTRL>
__device__ __forceinline__ float dpp_add(float x) {
    int t = __builtin_amdgcn_update_dpp(0, __float_as_int(x), CTRL, 0xF, 0xF, true);
    return x + __int_as_float(t);
}
__device__ __forceinline__ float wave_reduce(float s) {
    s = dpp_add<0x111>(s);   // row_shr:1
    s = dpp_add<0x112>(s);   // row_shr:2
    s = dpp_add<0x114>(s);   // row_shr:4
    s = dpp_add<0x118>(s);   // row_shr:8
    s = dpp_add<0x142>(s);   // row_bcast:15
    s = dpp_add<0x143>(s);   // row_bcast:31
    return __int_as_float(__builtin_amdgcn_readlane(__float_as_int(s), 63));
}

// ---------------- K2: persistent GRU scan ----------------
// 32 blocks x 512 threads. Block b owns h[32b..32b+32); wave w owns 4 of
// them (12 W_hh rows in VGPRs, pinned per-step). h exchanged as (val,tag)
// pairs multicast to 4 copies; consumers poll copy (b+w)&3 -> ~8 readers
// per cache line instead of 128. One barrier/step; no fences anywhere.
__global__ __launch_bounds__(512, 1)
void k_scan(const float* __restrict__ W_hh, const float* __restrict__ b_hh,
            float* ws) {
    __shared__ float hl[HDIM];          // 4 KB staged h

    const int b = blockIdx.x;
    const int tid = threadIdx.x;
    const int w = tid >> 6, ln = tid & 63;
    const int j0 = b * 32;
    const int jw = j0 + w * JPW;
    const int il = ln & 3;
    const int jme = jw + il;            // this lane-group's h index

    const float* gi = ws;
    unsigned* pairs = (unsigned*)(ws + PAIRS_OFF);
    const int csel = (b + w) & (NCOPY - 1);

    // ---- weights: 12 rows x 16 cols/lane in VGPRs ----
    f32x4 wr[ROWS][4];
    #pragma unroll
    for (int rr = 0; rr < ROWS; ++rr) {
        const int g = rr >> 2, i = rr & 3;
        const float* src = W_hh + (size_t)(g * HDIM + jw + i) * HDIM + ln * 4;
        #pragma unroll
        for (int c = 0; c < 4; ++c) wr[rr][c] = *(const f32x4*)(src + 256 * c);
    }

    const float br = b_hh[jme];
    const float bz = b_hh[HDIM + jme];
    const float bn = b_hh[2 * HDIM + jme];

    for (int t = 0; t < SEQ; ++t) {
        const unsigned tt = (unsigned)t;

        // pin weights in VGPRs THIS iteration (stops rematerialization)
        #pragma unroll
        for (int rr = 0; rr < ROWS; ++rr)
            asm volatile("" : "+v"(wr[rr][0]), "+v"(wr[rr][1]),
                              "+v"(wr[rr][2]), "+v"(wr[rr][3]));

        // gi prefetch (cached): in flight during the poll
        const float* gp = gi + (size_t)t * G3 + jme;
        const float gi_r = gp[0], gi_z = gp[HDIM], gi_n = gp[2 * HDIM];

        // ---- fused poll+load: lane ln covers pairs {128w+2ln, +1} ----
        unsigned* qb = pairs + csel * COPY_DW + ((t + 1) & 1) * 2048
                             + 256 * w + 4 * ln;
        u32x4 p;
        int spin = 0;
        for (;;) {
            asm volatile("global_load_dwordx4 %0, %1, off sc0 sc1\n\t"
                         "s_waitcnt vmcnt(0)"
                         : "=&v"(p) : "v"(qb) : "memory");
            if (__all((p.y == tt) & (p.w == tt))) break;
            if (++spin > (1 << 16)) break;      // fail visibly, never hang
        }
        f32x2 h2; h2.x = __uint_as_float(p.x); h2.y = __uint_as_float(p.z);
        *(f32x2*)&hl[128 * w + 2 * ln] = h2;
        __syncthreads();
        // (next-step hl overwrite is WAR-safe: a wave's step-t+1 staging is
        //  gated by all tags t+1, and every tag-t+1 store is data-dependent
        //  on that producer wave's hl reads of step t)

        const f32x4 hv0 = *(const f32x4*)&hl[ln * 4];
        const f32x4 hv1 = *(const f32x4*)&hl[ln * 4 + 256];
        const f32x4 hv2 = *(const f32x4*)&hl[ln * 4 + 512];
        const f32x4 hv3 = *(const f32x4*)&hl[ln * 4 + 768];
        const float hp  = hl[jme];

        #define DOT16(rr) ( \
            wr[rr][0].x*hv0.x + wr[rr][0].y*hv0.y + wr[rr][0].z*hv0.z + wr[rr][0].w*hv0.w + \
            wr[rr][1].x*hv1.x + wr[rr][1].y*hv1.y + wr[rr][1].z*hv1.z + wr[rr][1].w*hv1.w + \
            wr[rr][2].x*hv2.x + wr[rr][2].y*hv2.y + wr[rr][2].z*hv2.z + wr[rr][2].w*hv2.w + \
            wr[rr][3].x*hv3.x + wr[rr][3].y*hv3.y + wr[rr][3].z*hv3.z + wr[rr][3].w*hv3.w )

        float tot[ROWS];
        #pragma unroll
        for (int rr = 0; rr < ROWS; ++rr) tot[rr] = wave_reduce(DOT16(rr));
        #undef DOT16

        // ---- gate combine + multicast publish (lanes 0..3 per wave) ----
        if (ln < 4) {
            const float sr = (il == 0) ? tot[0] : (il == 1) ? tot[1] : (il == 2) ? tot[2]  : tot[3];
            const float sz = (il == 0) ? tot[4] : (il == 1) ? tot[5] : (il == 2) ? tot[6]  : tot[7];
            const float sn = (il == 0) ? tot[8] : (il == 1) ? tot[9] : (il == 2) ? tot[10] : tot[11];
            const float r = 1.0f / (1.0f + __expf(-(gi_r + sr + br)));
            const float z = 1.0f / (1.0f + __expf(-(gi_z + sz + bz)));
            const float n = tanhf(gi_n + r * (sn + bn));
            const float hnew = (1.0f - z) * n + z * hp;
            u32x2 pv; pv.x = __float_as_uint(hnew); pv.y = tt + 1u;
            unsigned* dst = pairs + (t & 1) * 2048 + (unsigned)jme * 2;
            #pragma unroll
            for (int c = 0; c < NCOPY; ++c)
                asm volatile("global_store_dwordx2 %0, %1, off sc0 sc1"
                             :: "v"(dst + c * COPY_DW), "v"(pv) : "memory");
        }
    }
}

// ---------------- K3: head ----------------
__global__ void k_head(const float* __restrict__ W1, const float* __restrict__ b1,
                       const float* __restrict__ W2, const float* __restrict__ b2,
                       const float* __restrict__ ws, float* __restrict__ out) {
    // final h: copy 0, buffer[4095&1=1], values at even dwords
    const unsigned* hpair = (const unsigned*)(ws + PAIRS_OFF) + 2048;
    const int ln = threadIdx.x;
    __shared__ float zsh[8];
    for (int m = 0; m < 8; ++m) {
        float s = 0.0f;
        #pragma unroll
        for (int c = 0; c < 16; ++c) {
            const int j = c * 64 + ln;
            s += __uint_as_float(hpair[2 * j]) * W1[m * HDIM + j];
        }
        #pragma unroll
        for (int off = 32; off; off >>= 1) s += __shfl_xor(s, off);
        if (ln == 0) zsh[m] = fmaxf(s + b1[m], 0.0f);
    }
    __syncthreads();
    if (ln < 2) {
        float s = b2[ln];
        #pragma unroll
        for (int m = 0; m < 8; ++m) s += zsh[m] * W2[ln * 8 + m];
        out[ln] = 1.0f / (1.0f + expf(-s));
    }
}

extern "C" void kernel_launch(void* const* d_in, const int* in_sizes, int n_in,
                              void* d_out, int out_size, void* d_ws, size_t ws_size,
                              hipStream_t stream) {
    const int*   X    = (const int*)d_in[0];
    const float* emb  = (const float*)d_in[1];
    const float* W_ih = (const float*)d_in[2];
    const float* W_hh = (const float*)d_in[3];
    const float* b_ih = (const float*)d_in[4];
    const float* b_hh = (const float*)d_in[5];
    const float* W1   = (const float*)d_in[6];
    const float* b1   = (const float*)d_in[7];
    const float* W2   = (const float*)d_in[8];
    const float* b2   = (const float*)d_in[9];
    float* out = (float*)d_out;
    float* ws  = (float*)d_ws;

    if (ws_size < WS_NEEDED_BYTES) {
        k_ws_too_small<<<1, 64, 0, stream>>>(out);
        return;
    }

    k_init<<<dim3(32), dim3(256), 0, stream>>>(ws);
    dim3 g1(SEQ / 64, G3 / 64);
    k_gi<<<g1, dim3(256), 0, stream>>>(X, emb, W_ih, b_ih, ws);
    k_scan<<<dim3(NBLK), dim3(512), 0, stream>>>(W_hh, b_hh, ws);
    k_head<<<dim3(1), dim3(64), 0, stream>>>(W1, b1, W2, b2, ws, out);
}